// Round 1
// baseline (43.456 us; speedup 1.0000x reference)
//
#include <hip/hip_runtime.h>

// Elementwise clip: out[i] = min(max(Y_hat[i], obs[2i+0]), obs[2i+1])
// B = 16777216 elements, fp32. 16 B/elem HBM traffic -> memory bound.
// Vectorized: each thread handles 4 elements per grid-stride iteration:
//   1x float4 load (Y_hat), 2x float4 load (obs pairs), 1x float4 store.

__global__ void clip_kernel(const float* __restrict__ yhat,
                            const float* __restrict__ obs,
                            float* __restrict__ out,
                            int n4 /* number of float4 groups */) {
    const float4* __restrict__ y4 = reinterpret_cast<const float4*>(yhat);
    const float4* __restrict__ o4 = reinterpret_cast<const float4*>(obs);
    float4* __restrict__ out4 = reinterpret_cast<float4*>(out);

    int stride = gridDim.x * blockDim.x;
    for (int i = blockIdx.x * blockDim.x + threadIdx.x; i < n4; i += stride) {
        float4 y = y4[i];
        float4 oa = o4[2 * i];       // (lo0, hi0, lo1, hi1)
        float4 ob = o4[2 * i + 1];   // (lo2, hi2, lo3, hi3)

        float4 r;
        r.x = fminf(fmaxf(y.x, oa.x), oa.y);
        r.y = fminf(fmaxf(y.y, oa.z), oa.w);
        r.z = fminf(fmaxf(y.z, ob.x), ob.y);
        r.w = fminf(fmaxf(y.w, ob.z), ob.w);

        out4[i] = r;
    }
}

extern "C" void kernel_launch(void* const* d_in, const int* in_sizes, int n_in,
                              void* d_out, int out_size, void* d_ws, size_t ws_size,
                              hipStream_t stream) {
    const float* yhat = (const float*)d_in[0];  // (B,1) fp32
    const float* obs  = (const float*)d_in[1];  // (B,2) fp32 interleaved
    float* out = (float*)d_out;                 // (B,1) fp32

    int n = in_sizes[0];      // B
    int n4 = n >> 2;          // B divisible by 4 (B = 2^24)

    const int block = 256;
    int grid = (n4 + block - 1) / block;
    if (grid > 2048) grid = 2048;   // grid-stride the rest

    clip_kernel<<<grid, block, 0, stream>>>(yhat, obs, out, n4);
}